// Round 6
// baseline (987.853 us; speedup 1.0000x reference)
//
#include <hip/hip_runtime.h>
#include <hip/hip_bf16.h>
#include <math.h>

#define HIDDEN 192
#define NBINS 10
#define PROJ 29          // 3*NBINS-1
#define TAILF 5.0f
#define NLAYERS 3
#define NB 64
#define NT 2048
#define TT 32
#define HALO 13
#define COLS (TT + 2*HALO)   // 58
#define HS 58                 // hb bf16 row stride (29 dwords, odd -> conflict-free cols)
#define YT_ROWS 56            // max live cols (layer 0)
#define YS 194                // Yt bf16 row stride (97 dwords, odd)
#define NTB (NT/TT)           // 64
#define LN_EPS 1e-5f
#define MIN_BIN 1e-3f
#define MIN_DERF 1e-3f
#define INV_SQRTF 0.07216878364870323f   // 1/sqrt(192)
#define THREADS 512
#define NWAVES 8

// LDS layout: shorts first, then f32 section
#define HB_SHORTS (HIDDEN*HS)                 // 11136
#define YT_SHORTS (YT_ROWS*YS)                // 10864
#define OFF_F32 ((HB_SHORTS + YT_SHORTS)/2)   // float index: 11000
#define N_LNP (NLAYERS*2*HIDDEN)              // 1152 packed (g,b) dwords
#define SMEM_FLOATS (OFF_F32 + COLS + N_LNP)  // 12210 floats = 48840 B

#define WS_PART_BYTES 16384
#define WBF_ELEMS (NLAYERS*HIDDEN*HIDDEN)

typedef __attribute__((ext_vector_type(8))) short bf16x8;
typedef __attribute__((ext_vector_type(4))) float f32x4;

__device__ __forceinline__ unsigned short f2bf(float f) {
    __hip_bfloat16 h = __float2bfloat16(f);
    return __builtin_bit_cast(unsigned short, h);
}
__device__ __forceinline__ unsigned packbf(float lo, float hi_) {
    return (unsigned)f2bf(lo) | ((unsigned)f2bf(hi_) << 16);
}
__device__ __forceinline__ float bf2f_lo(unsigned u) {
    union { unsigned u; float f; } c; c.u = u << 16; return c.f;
}
__device__ __forceinline__ float bf2f_hi(unsigned u) {
    union { unsigned u; float f; } c; c.u = u & 0xffff0000u; return c.f;
}
__device__ __forceinline__ float bfs(unsigned short s) {
    union { unsigned u; float f; } c; c.u = ((unsigned)s) << 16; return c.f;
}

// exact GELU via A&S 7.1.26 rational erf (|err| < 1.5e-7), hw rcp/exp2
__device__ __forceinline__ float gelu_fast(float x) {
    const float az = fabsf(x) * 0.7071067811865476f;
    const float t  = __builtin_amdgcn_rcpf(fmaf(0.3275911f, az, 1.0f));
    float p = fmaf(1.061405429f, t, -1.453152027f);
    p = fmaf(p, t, 1.421413741f);
    p = fmaf(p, t, -0.284496736f);
    p = fmaf(p, t, 0.254829592f);
    p = p * t;
    const float e  = __builtin_amdgcn_exp2f(az*az*(-1.4426950408889634f));
    const float er = fmaf(-p, e, 1.0f);            // erf(|x|/sqrt2)
    const float se = (x >= 0.0f) ? er : -er;
    return 0.5f * x * (1.0f + se);
}
__device__ __forceinline__ float softplus_f(float x) {
    return (x > 20.0f) ? x : log1pf(expf(x));
}
__device__ __forceinline__ float wave_sum(float v) {
    #pragma unroll
    for (int o = 32; o > 0; o >>= 1) v += __shfl_xor(v, o, 64);
    return v;
}

// LN over channels for one Yt row r = tid>>3 (8 lanes/row, 24 ch/lane) + GELU.
// toYt: rows [0,nc) processed in place; rows [nc,YT_ROWS) zeroed; rows >= YT_ROWS skipped.
// else: rows [0,nc) residual-added into hb (bf16) at column r+jlo.
__device__ __forceinline__ void ln_pass(unsigned short* yt, unsigned short* hbs,
                                        const unsigned* gb,
                                        int tid, int jlo, int nc, bool toYt) {
    const int r = tid >> 3, q = tid & 7;
    const int c0 = q * 24;
    unsigned short* row = yt + r * YS;
    unsigned* wp = (unsigned*)(row + c0);
    if (r >= nc) {
        if (toYt && r < YT_ROWS) {
            #pragma unroll
            for (int i = 0; i < 12; ++i) wp[i] = 0u;
        }
        return;
    }
    const unsigned* rp = (const unsigned*)(row + c0);
    float v[24];
    float s = 0.0f, ss = 0.0f;
    #pragma unroll
    for (int i = 0; i < 12; ++i) {
        unsigned u = rp[i];
        float a = bf2f_lo(u), c = bf2f_hi(u);
        v[2*i] = a; v[2*i+1] = c;
        s += a + c; ss += a*a + c*c;
    }
    s  += __shfl_xor(s, 1, 64);  s  += __shfl_xor(s, 2, 64);  s  += __shfl_xor(s, 4, 64);
    ss += __shfl_xor(ss, 1, 64); ss += __shfl_xor(ss, 2, 64); ss += __shfl_xor(ss, 4, 64);
    const float mu  = s * (1.0f/HIDDEN);
    const float var = fmaxf(ss * (1.0f/HIDDEN) - mu*mu, 0.0f);
    const float rs  = rsqrtf(var + LN_EPS);

    float gv[24], bv[24];
    #pragma unroll
    for (int i = 0; i < 24; ++i) {
        unsigned u = gb[c0 + i];
        gv[i] = bf2f_lo(u); bv[i] = bf2f_hi(u);
    }
    if (toYt) {
        #pragma unroll
        for (int i = 0; i < 12; ++i) {
            float r0 = gelu_fast((v[2*i]   - mu)*rs*gv[2*i]   + bv[2*i]);
            float r1 = gelu_fast((v[2*i+1] - mu)*rs*gv[2*i+1] + bv[2*i+1]);
            wp[i] = packbf(r0, r1);
        }
    } else {
        const int col = r + jlo;
        #pragma unroll
        for (int i = 0; i < 24; ++i) {
            float rr = gelu_fast((v[i] - mu)*rs*gv[i] + bv[i]);
            const int idx = (c0 + i)*HS + col;
            hbs[idx] = f2bf(bfs(hbs[idx]) + rr);
        }
    }
}

__global__ void wconv_kernel(const float* __restrict__ pww, unsigned short* __restrict__ wbf) {
    int i = blockIdx.x * 1024 + threadIdx.x;
    if (i < WBF_ELEMS) wbf[i] = f2bf(pww[i]);
}

__global__ __launch_bounds__(THREADS) void vits_fused(
    const float* __restrict__ inputs, const float* __restrict__ pmask,
    const float* __restrict__ cpw, const float* __restrict__ cpb,
    const float* __restrict__ dww, const float* __restrict__ dwb,
    const float* __restrict__ pww, const float* __restrict__ pwb,
    const float* __restrict__ g1, const float* __restrict__ b1,
    const float* __restrict__ g2, const float* __restrict__ b2,
    const float* __restrict__ pjw, const float* __restrict__ pjb,
    float* __restrict__ out, float* __restrict__ part,
    const unsigned short* __restrict__ wbf, int preW)
{
    extern __shared__ float sm[];
    unsigned short* hbs = (unsigned short*)sm;
    unsigned short* yt  = hbs + HB_SHORTS;
    float* mk = sm + OFF_F32;
    unsigned* lnpp = (unsigned*)(mk + COLS);   // [L][{ln1,ln2}][192] packed (g,b)

    const int tid = threadIdx.x;
    const int lane = tid & 63;
    const int wid = tid >> 6;
    const int wu  = __builtin_amdgcn_readfirstlane(wid);
    const int b  = blockIdx.x / NTB;
    const int tb = blockIdx.x % NTB;
    const int t0 = tb*TT - HALO;

    // ---- stage packed LN params into LDS ----
    for (int i = tid; i < N_LNP; i += THREADS) {
        const int L = i / (2*HIDDEN);
        const int r = i - L*2*HIDDEN;
        const int which = r / HIDDEN;
        const int c = r - which*HIDDEN;
        const float* gp = which ? g2 : g1;
        const float* bp = which ? b2 : b1;
        lnpp[i] = packbf(gp[L*HIDDEN + c], bp[L*HIDDEN + c]);
    }

    // ---- load mask tile (zero outside [0,T)) ----
    if (tid < COLS) {
        int t = t0 + tid;
        bool in = (t >= 0) && (t < NT);
        mk[tid] = in ? pmask[(size_t)b*NT + t] : 0.0f;
    }
    __syncthreads();

    // ---- h = conv_pre (outer product, HALF==1), row-per-wave ----
    {
        float fvv = 0.0f;
        if (lane < COLS) {
            int t = t0 + lane;
            bool in = (t >= 0) && (t < NT);
            fvv = in ? inputs[(size_t)b*2*NT + t] : 0.0f;
        }
        for (int c = wu; c < HIDDEN; c += NWAVES) {
            const float wv = cpw[c], bv = cpb[c];
            if (lane < COLS)
                hbs[c*HS + lane] = f2bf(wv*fvv + bv);
        }
    }
    __syncthreads();

    const int dils[NLAYERS]  = {1, 3, 9};
    const int mouts[NLAYERS] = {1, 4, 13};

    const int l15 = lane & 15, hi = lane >> 4;
    const int mgrp = wu & 3;    // 0..3 -> M offset mgrp*48 (3 M-tiles)
    const int ngrp = wu >> 2;   // 0..1 -> N offset ngrp*32 (2 N-tiles)

    for (int L = 0; L < NLAYERS; ++L) {
        const int dil = dils[L];
        const int jlo = mouts[L], jhi = COLS - mouts[L];
        const int nc  = jhi - jlo;   // 56 / 50 / 32

        // ---- depthwise dilated conv + bias -> Yt (bf16, rows = col - jlo) ----
        {
            const int jA = jlo + lane;
            const bool act = jA < jhi;   // lane < nc
            float mA0 = 0.f, mA1 = 0.f, mA2 = 0.f;
            if (act) { mA0 = mk[jA-dil]; mA1 = mk[jA]; mA2 = mk[jA+dil]; }
            for (int c = wu; c < HIDDEN; c += NWAVES) {
                const float* w = dww + ((size_t)L*HIDDEN + c)*3;
                const float w0 = w[0], w1 = w[1], w2 = w[2];
                const float bv = dwb[L*HIDDEN + c];
                const unsigned short* hrow = hbs + c*HS;
                if (act) {
                    float vA = bv + w0*bfs(hrow[jA-dil])*mA0
                                  + w1*bfs(hrow[jA    ])*mA1
                                  + w2*bfs(hrow[jA+dil])*mA2;
                    yt[lane*YS + c] = f2bf(vA);
                }
            }
        }
        __syncthreads();

        // ---- LN1 + GELU in place on Yt (rows [nc,56) zeroed) ----
        ln_pass(yt, hbs, lnpp + (L*2+0)*HIDDEN, tid, jlo, nc, true);
        __syncthreads();

        // ---- pointwise 192x192 GEMM via MFMA (bf16 in, f32 acc), N=64 ----
        {
            bf16x8 Bf[2][6];
            #pragma unroll
            for (int nt = 0; nt < 2; ++nt) {
                const int n = ngrp*32 + nt*16 + l15;
                const int row = (n < YT_ROWS) ? n : (YT_ROWS - 1);
                const unsigned short* yr = yt + row*YS;
                #pragma unroll
                for (int ks = 0; ks < 6; ++ks) {
                    const unsigned* p = (const unsigned*)(yr + ks*32 + hi*8);
                    union { unsigned u[4]; bf16x8 v; } cv;
                    cv.u[0] = p[0]; cv.u[1] = p[1]; cv.u[2] = p[2]; cv.u[3] = p[3];
                    Bf[nt][ks] = cv.v;
                }
            }
            f32x4 acc[3][2];
            #pragma unroll
            for (int mt = 0; mt < 3; ++mt)
                #pragma unroll
                for (int nt = 0; nt < 2; ++nt)
                    acc[mt][nt] = (f32x4){0.0f, 0.0f, 0.0f, 0.0f};

            if (preW) {
                const unsigned short* wbl = wbf + (size_t)L*HIDDEN*HIDDEN;
                #pragma unroll
                for (int mt = 0; mt < 3; ++mt) {
                    const int m = mgrp*48 + mt*16 + l15;
                    const unsigned short* wr = wbl + (size_t)m*HIDDEN + hi*8;
                    #pragma unroll
                    for (int ks = 0; ks < 6; ++ks) {
                        bf16x8 a = *(const bf16x8*)(wr + ks*32);
                        acc[mt][0] = __builtin_amdgcn_mfma_f32_16x16x32_bf16(a, Bf[0][ks], acc[mt][0], 0, 0, 0);
                        acc[mt][1] = __builtin_amdgcn_mfma_f32_16x16x32_bf16(a, Bf[1][ks], acc[mt][1], 0, 0, 0);
                    }
                }
            } else {
                const float* wlayer = pww + (size_t)L*HIDDEN*HIDDEN;
                #pragma unroll
                for (int mt = 0; mt < 3; ++mt) {
                    const int m = mgrp*48 + mt*16 + l15;
                    const float* wr = wlayer + (size_t)m*HIDDEN + hi*8;
                    #pragma unroll
                    for (int ks = 0; ks < 6; ++ks) {
                        float4 a0 = *(const float4*)(wr + ks*32);
                        float4 a1 = *(const float4*)(wr + ks*32 + 4);
                        bf16x8 a;
                        a[0] = (short)f2bf(a0.x); a[1] = (short)f2bf(a0.y);
                        a[2] = (short)f2bf(a0.z); a[3] = (short)f2bf(a0.w);
                        a[4] = (short)f2bf(a1.x); a[5] = (short)f2bf(a1.y);
                        a[6] = (short)f2bf(a1.z); a[7] = (short)f2bf(a1.w);
                        acc[mt][0] = __builtin_amdgcn_mfma_f32_16x16x32_bf16(a, Bf[0][ks], acc[mt][0], 0, 0, 0);
                        acc[mt][1] = __builtin_amdgcn_mfma_f32_16x16x32_bf16(a, Bf[1][ks], acc[mt][1], 0, 0, 0);
                    }
                }
            }
            __syncthreads();   // all Yt reads complete before overwrite

            // bias + write z back over Yt (bf16), rows < YT_ROWS only
            #pragma unroll
            for (int mt = 0; mt < 3; ++mt) {
                const int mrow = mgrp*48 + mt*16 + hi*4;
                float4 bias = *(const float4*)(pwb + L*HIDDEN + mrow);
                #pragma unroll
                for (int nt = 0; nt < 2; ++nt) {
                    const int n = ngrp*32 + nt*16 + l15;
                    if (n < YT_ROWS) {
                        unsigned* zr = (unsigned*)(yt + n*YS + mrow);
                        f32x4 v = acc[mt][nt];
                        zr[0] = packbf(v[0] + bias.x, v[1] + bias.y);
                        zr[1] = packbf(v[2] + bias.z, v[3] + bias.w);
                    }
                }
            }
        }
        __syncthreads();

        // ---- LN2 + GELU + residual into hb (bf16) ----
        ln_pass(yt, hbs, lnpp + (L*2+1)*HIDDEN, tid, jlo, nc, false);
        __syncthreads();
    }

    // ---- projection: wave w handles o = w+8k (scalar weights), lanes 0..31 = cols ----
    float* pb = (float*)yt;   // [TT][33], yt dead
    {
        const int j = lane;
        const int jj = HALO + j;
        #pragma unroll
        for (int k = 0; k < 4; ++k) {
            const int o = wu + 8*k;
            if (o < PROJ && j < TT) {
                const float* w = pjw + (size_t)o*HIDDEN;
                const float mkv = mk[jj];
                float acc = 0.0f;
                #pragma unroll 4
                for (int c = 0; c < HIDDEN; ++c)
                    acc = fmaf(w[c], bfs(hbs[c*HS + jj]), acc);
                pb[j*33 + o] = acc*mkv + pjb[o];
            }
        }
    }
    __syncthreads();

    // ---- spline epilogue: lanes 0..31 of wave 0; scratch over hb ----
    float* sc = sm;   // hb region dead after projection
    float ladm = 0.0f;
    if (tid < TT) {
        const int j  = tid;
        const int t  = tb*TT + j;
        const int jj = HALO + j;
        float* S  = sc + j*57;
        float* cw = S;          // 11
        float* ch = S + 11;     // 11
        float* wd = S + 22;     // 10
        float* ht = S + 32;     // 10
        float* dv = S + 42;     // 11

        const float x  = inputs[(size_t)b*2*NT + NT + t];
        const float fvv = inputs[(size_t)b*2*NT + t];
        const float mv = mk[jj];

        {
            float u[NBINS]; float m = -1e30f;
            #pragma unroll
            for (int k = 0; k < NBINS; ++k) { u[k] = pb[j*33 + k]*INV_SQRTF; m = fmaxf(m, u[k]); }
            float se = 0.0f;
            #pragma unroll
            for (int k = 0; k < NBINS; ++k) { u[k] = expf(u[k] - m); se += u[k]; }
            float inv = 1.0f/se, csum = 0.0f;
            cw[0] = -TAILF;
            #pragma unroll
            for (int k = 0; k < NBINS; ++k) {
                float wk = MIN_BIN + (1.0f - NBINS*MIN_BIN)*u[k]*inv;
                csum += wk;
                cw[k+1] = 2.0f*TAILF*csum - TAILF;
            }
            cw[NBINS] = TAILF;
            #pragma unroll
            for (int k = 0; k < NBINS; ++k) wd[k] = cw[k+1] - cw[k];
        }
        {
            float u[NBINS]; float m = -1e30f;
            #pragma unroll
            for (int k = 0; k < NBINS; ++k) { u[k] = pb[j*33 + 10 + k]*INV_SQRTF; m = fmaxf(m, u[k]); }
            float se = 0.0f;
            #pragma unroll
            for (int k = 0; k < NBINS; ++k) { u[k] = expf(u[k] - m); se += u[k]; }
            float inv = 1.0f/se, csum = 0.0f;
            ch[0] = -TAILF;
            #pragma unroll
            for (int k = 0; k < NBINS; ++k) {
                float wk = MIN_BIN + (1.0f - NBINS*MIN_BIN)*u[k]*inv;
                csum += wk;
                ch[k+1] = 2.0f*TAILF*csum - TAILF;
            }
            ch[NBINS] = TAILF;
            #pragma unroll
            for (int k = 0; k < NBINS; ++k) ht[k] = ch[k+1] - ch[k];
        }
        {
            const float cpad = logf(expf(1.0f - MIN_DERF) - 1.0f);
            float edge = MIN_DERF + softplus_f(cpad);
            dv[0] = edge;
            #pragma unroll
            for (int k = 0; k < NBINS-1; ++k) dv[k+1] = MIN_DERF + softplus_f(pb[j*33 + 2*NBINS + k]);
            dv[NBINS] = edge;
        }

        const float xi = fminf(fmaxf(x, -TAILF), TAILF);
        int cnt = 0;
        #pragma unroll
        for (int k = 0; k <= NBINS; ++k) {
            float bl = cw[k] + ((k == NBINS) ? 1e-6f : 0.0f);
            cnt += (xi >= bl) ? 1 : 0;
        }
        int bi = cnt - 1;
        bi = (bi < 0) ? 0 : ((bi > NBINS-1) ? NBINS-1 : bi);

        const float in_cw = cw[bi], in_w = wd[bi];
        const float in_ch = ch[bi], in_h = ht[bi];
        const float in_d  = ht[bi]/wd[bi];
        const float dA = dv[bi], dB = dv[bi+1];
        const float i1 = dA + dB - 2.0f*in_d;
        const float th = (xi - in_cw)/in_w;
        const float t1m = th*(1.0f - th);
        const float den = in_d + i1*t1m;
        const float outv = in_ch + in_h*(in_d*th*th + dA*t1m)/den;
        const float omt = 1.0f - th;
        const float dnum = in_d*in_d*(dB*th*th + 2.0f*in_d*t1m + dA*omt*omt);
        const float lad = logf(dnum) - 2.0f*logf(den);

        const bool inside = (x >= -TAILF) && (x <= TAILF);
        const float sec  = inside ? outv : x;
        ladm = (inside ? lad : 0.0f) * mv;

        out[(size_t)b*2*NT + t]      = fvv*mv;
        out[(size_t)b*2*NT + NT + t] = sec*mv;
    }
    if (tid < 64) {
        float tot = wave_sum(ladm);
        if (lane == 0) part[b*NTB + tb] = tot;
    }
}

__global__ void ld_reduce(const float* __restrict__ part, float* __restrict__ ld) {
    int b = threadIdx.x;
    if (b < NB) {
        float s = 0.0f;
        for (int k = 0; k < NTB; ++k) s += part[b*NTB + k];
        ld[b] = s;
    }
}

extern "C" void kernel_launch(void* const* d_in, const int* in_sizes, int n_in,
                              void* d_out, int out_size, void* d_ws, size_t ws_size,
                              hipStream_t stream) {
    const float* inputs = (const float*)d_in[0];
    const float* pmask  = (const float*)d_in[1];
    const float* cpw    = (const float*)d_in[2];
    const float* cpb    = (const float*)d_in[3];
    const float* dww    = (const float*)d_in[4];
    const float* dwb    = (const float*)d_in[5];
    const float* pww    = (const float*)d_in[6];
    const float* pwb    = (const float*)d_in[7];
    const float* g1     = (const float*)d_in[8];
    const float* b1     = (const float*)d_in[9];
    const float* g2     = (const float*)d_in[10];
    const float* b2     = (const float*)d_in[11];
    const float* pjw    = (const float*)d_in[12];
    const float* pjb    = (const float*)d_in[13];
    float* out  = (float*)d_out;
    float* part = (float*)d_ws;

    const size_t need = WS_PART_BYTES + (size_t)WBF_ELEMS*2;
    const int preW = (ws_size >= need) ? 1 : 0;
    unsigned short* wbf = (unsigned short*)((char*)d_ws + WS_PART_BYTES);

    if (preW) {
        wconv_kernel<<<(WBF_ELEMS + 1023)/1024, 1024, 0, stream>>>(pww, wbf);
    }

    const size_t smem = (size_t)SMEM_FLOATS * sizeof(float);
    hipFuncSetAttribute(reinterpret_cast<const void*>(vits_fused),
                        hipFuncAttributeMaxDynamicSharedMemorySize, (int)smem);
    vits_fused<<<NB*NTB, THREADS, smem, stream>>>(inputs, pmask, cpw, cpb, dww, dwb,
                                                  pww, pwb, g1, b1, g2, b2, pjw, pjb,
                                                  out, part, wbf, preW);
    ld_reduce<<<1, 64, 0, stream>>>(part, out + (size_t)NB*2*NT);
}

// Round 7
// 546.625 us; speedup vs baseline: 1.8072x; 1.8072x over previous
//
#include <hip/hip_runtime.h>
#include <hip/hip_bf16.h>
#include <math.h>

#define HIDDEN 192
#define NBINS 10
#define PROJ 29          // 3*NBINS-1
#define TAILF 5.0f
#define NLAYERS 3
#define NB 64
#define NT 2048
#define TT 64
#define HALO 13
#define COLS (TT + 2*HALO)   // 90
#define HS 94                 // hb bf16 row stride (47 dwords, odd -> conflict-free cols)
#define NPAD 96               // GEMM N padded
#define YS 194                // Yt bf16 row stride (97 dwords, odd)
#define NBLK (NT/(2*TT))      // 16 blocks per batch row (2 tiles per block)
#define NTB 32                // part entries per batch row
#define LN_EPS 1e-5f
#define MIN_BIN 1e-3f
#define MIN_DERF 1e-3f
#define INV_SQRTF 0.07216878364870323f   // 1/sqrt(192)
#define THREADS 768
#define NWAVES 12

// LDS layout: shorts [hb0][hb1][yt0][yt1], then f32 [mk0][mk1][lnpp]
#define HB_SHORTS (HIDDEN*HS)                 // 18048
#define YT_SHORTS (NPAD*YS)                   // 18624
#define OFF_F32 ((2*HB_SHORTS + 2*YT_SHORTS)/2)   // dword index 36672
#define N_LNP (NLAYERS*2*HIDDEN)              // 1152 packed (g,b) dwords
#define SMEM_FLOATS (OFF_F32 + 2*COLS + N_LNP)    // 38004 dwords = 152016 B

#define WS_PART_BYTES 16384
#define WBF_ELEMS (NLAYERS*HIDDEN*HIDDEN)

typedef __attribute__((ext_vector_type(8))) short bf16x8;
typedef __attribute__((ext_vector_type(4))) float f32x4;

__device__ __forceinline__ unsigned short f2bf(float f) {
    __hip_bfloat16 h = __float2bfloat16(f);
    return __builtin_bit_cast(unsigned short, h);
}
__device__ __forceinline__ unsigned packbf(float lo, float hi_) {
    return (unsigned)f2bf(lo) | ((unsigned)f2bf(hi_) << 16);
}
__device__ __forceinline__ float bf2f_lo(unsigned u) {
    union { unsigned u; float f; } c; c.u = u << 16; return c.f;
}
__device__ __forceinline__ float bf2f_hi(unsigned u) {
    union { unsigned u; float f; } c; c.u = u & 0xffff0000u; return c.f;
}
__device__ __forceinline__ float bfs(unsigned short s) {
    union { unsigned u; float f; } c; c.u = ((unsigned)s) << 16; return c.f;
}

// exact GELU via A&S 7.1.26 rational erf (|err| < 1.5e-7), hw rcp/exp2
__device__ __forceinline__ float gelu_fast(float x) {
    const float az = fabsf(x) * 0.7071067811865476f;
    const float t  = __builtin_amdgcn_rcpf(fmaf(0.3275911f, az, 1.0f));
    float p = fmaf(1.061405429f, t, -1.453152027f);
    p = fmaf(p, t, 1.421413741f);
    p = fmaf(p, t, -0.284496736f);
    p = fmaf(p, t, 0.254829592f);
    p = p * t;
    const float e  = __builtin_amdgcn_exp2f(az*az*(-1.4426950408889634f));
    const float er = fmaf(-p, e, 1.0f);            // erf(|x|/sqrt2)
    const float se = (x >= 0.0f) ? er : -er;
    return 0.5f * x * (1.0f + se);
}
__device__ __forceinline__ float softplus_f(float x) {
    return (x > 20.0f) ? x : log1pf(expf(x));
}
__device__ __forceinline__ float wave_sum(float v) {
    #pragma unroll
    for (int o = 32; o > 0; o >>= 1) v += __shfl_xor(v, o, 64);
    return v;
}

// LN over channels for one column (8 lanes/col, 24 ch/lane) + GELU.
// toYt: write back to Yt (bf16); dead cols -> zeros (no math).
// else: residual-add gelu*mk into pre-masked hb (bf16); dead cols skipped.
__device__ __forceinline__ void ln_pass(unsigned short* yt, unsigned short* hbs,
                                        const unsigned* gb, const float* mkp,
                                        int tid, int jlo, int jhi, bool toYt) {
    const int col = tid >> 3, q = tid & 7;
    const int c0 = q * 24;
    unsigned short* row = yt + col * YS;
    unsigned* wp = (unsigned*)(row + c0);
    if (col < jlo || col >= jhi) {
        if (toYt) {
            #pragma unroll
            for (int i = 0; i < 12; ++i) wp[i] = 0u;
        }
        return;
    }
    const unsigned* rp = (const unsigned*)(row + c0);
    float v[24];
    float s = 0.0f, ss = 0.0f;
    #pragma unroll
    for (int i = 0; i < 12; ++i) {
        unsigned u = rp[i];
        float a = bf2f_lo(u), c = bf2f_hi(u);
        v[2*i] = a; v[2*i+1] = c;
        s += a + c; ss += a*a + c*c;
    }
    s  += __shfl_xor(s, 1, 64);  s  += __shfl_xor(s, 2, 64);  s  += __shfl_xor(s, 4, 64);
    ss += __shfl_xor(ss, 1, 64); ss += __shfl_xor(ss, 2, 64); ss += __shfl_xor(ss, 4, 64);
    const float mu  = s * (1.0f/HIDDEN);
    const float var = fmaxf(ss * (1.0f/HIDDEN) - mu*mu, 0.0f);
    const float rs  = rsqrtf(var + LN_EPS);

    float gv[24], bv[24];
    #pragma unroll
    for (int i = 0; i < 24; ++i) {
        unsigned u = gb[c0 + i];
        gv[i] = bf2f_lo(u); bv[i] = bf2f_hi(u);
    }
    if (toYt) {
        #pragma unroll
        for (int i = 0; i < 12; ++i) {
            float r0 = gelu_fast((v[2*i]   - mu)*rs*gv[2*i]   + bv[2*i]);
            float r1 = gelu_fast((v[2*i+1] - mu)*rs*gv[2*i+1] + bv[2*i+1]);
            wp[i] = packbf(r0, r1);
        }
    } else {
        const float mkv = mkp[col];
        #pragma unroll
        for (int i = 0; i < 24; ++i) {
            float rr = gelu_fast((v[i] - mu)*rs*gv[i] + bv[i]) * mkv;
            const int idx = (c0 + i)*HS + col;
            hbs[idx] = f2bf(bfs(hbs[idx]) + rr);
        }
    }
}

__global__ void wconv_kernel(const float* __restrict__ pww, unsigned short* __restrict__ wbf) {
    int i = blockIdx.x * 1024 + threadIdx.x;
    if (i < WBF_ELEMS) wbf[i] = f2bf(pww[i]);
}

__global__ __launch_bounds__(THREADS) void vits_fused(
    const float* __restrict__ inputs, const float* __restrict__ pmask,
    const float* __restrict__ cpw, const float* __restrict__ cpb,
    const float* __restrict__ dww, const float* __restrict__ dwb,
    const float* __restrict__ pww, const float* __restrict__ pwb,
    const float* __restrict__ g1, const float* __restrict__ b1,
    const float* __restrict__ g2, const float* __restrict__ b2,
    const float* __restrict__ pjw, const float* __restrict__ pjb,
    float* __restrict__ out, float* __restrict__ part,
    const unsigned short* __restrict__ wbf, int preW)
{
    extern __shared__ float sm[];
    unsigned short* hb0 = (unsigned short*)sm;
    unsigned short* hb1 = hb0 + HB_SHORTS;
    unsigned short* yt0 = hb1 + HB_SHORTS;
    unsigned short* yt1 = yt0 + YT_SHORTS;
    float* mk0 = sm + OFF_F32;
    float* mk1 = mk0 + COLS;
    unsigned* lnpp = (unsigned*)(mk1 + COLS);   // [L][{ln1,ln2}][192] packed (g,b)

    const int tid = threadIdx.x;
    const int lane = tid & 63;
    const int wid = tid >> 6;
    const int wu  = __builtin_amdgcn_readfirstlane(wid);
    const int b   = blockIdx.x / NBLK;
    const int tbb = blockIdx.x % NBLK;

    // ---- stage packed LN params + mask tiles ----
    for (int i = tid; i < N_LNP; i += THREADS) {
        const int L = i / (2*HIDDEN);
        const int r = i - L*2*HIDDEN;
        const int which = r / HIDDEN;
        const int c = r - which*HIDDEN;
        const float* gp = which ? g2 : g1;
        const float* bp = which ? b2 : b1;
        lnpp[i] = packbf(gp[L*HIDDEN + c], bp[L*HIDDEN + c]);
    }
    for (int i = tid; i < 2*COLS; i += THREADS) {
        const int u = i / COLS, j = i - u*COLS;
        const int t = (tbb*2 + u)*TT - HALO + j;
        const bool in = (t >= 0) && (t < NT);
        (u ? mk1 : mk0)[j] = in ? pmask[(size_t)b*NT + t] : 0.0f;
    }
    __syncthreads();

    // ---- conv_pre: hm = (cpw*fv + cpb) * mask (pre-masked residual stream) ----
    #pragma unroll
    for (int u = 0; u < 2; ++u) {
        unsigned short* hbU = u ? hb1 : hb0;
        const float* mkU = u ? mk1 : mk0;
        const int t0u = (tbb*2 + u)*TT - HALO;
        float fA = 0.0f, fB = 0.0f;
        { int t = t0u + lane; if (t >= 0 && t < NT) fA = inputs[(size_t)b*2*NT + t]; }
        { int t = t0u + 64 + lane; if (lane + 64 < COLS && t >= 0 && t < NT) fB = inputs[(size_t)b*2*NT + t]; }
        const float mA = mkU[lane];
        const float mB = (lane + 64 < COLS) ? mkU[lane + 64] : 0.0f;
        for (int c = wu; c < HIDDEN; c += NWAVES) {
            const float wv = cpw[c], bv = cpb[c];
            hbU[c*HS + lane] = f2bf((wv*fA + bv)*mA);
            if (lane + 64 < COLS) hbU[c*HS + lane + 64] = f2bf((wv*fB + bv)*mB);
        }
    }
    __syncthreads();

    const int dils[NLAYERS]  = {1, 3, 9};
    const int mouts[NLAYERS] = {1, 4, 13};

    const int l15 = lane & 15, hi = lane >> 4;
    const int mgrp = wu & 3;    // 0..3 -> M offset mgrp*48
    const int ngrp = wu >> 2;   // 0..2 -> N offset ngrp*32

    for (int L = 0; L < NLAYERS; ++L) {
        const int dil = dils[L];
        const int jlo = mouts[L], jhi = COLS - mouts[L];

        // ---- depthwise dilated conv + bias -> Yt (input pre-masked: no mk muls) ----
        #pragma unroll
        for (int u = 0; u < 2; ++u) {
            unsigned short* hbU = u ? hb1 : hb0;
            unsigned short* ytU = u ? yt1 : yt0;
            const int jA = jlo + lane;
            const int jB = jlo + 64 + lane;
            const bool actB = jB < jhi;
            for (int c = wu; c < HIDDEN; c += NWAVES) {
                const float* w = dww + ((size_t)L*HIDDEN + c)*3;
                const float w0 = w[0], w1 = w[1], w2 = w[2];
                const float bv = dwb[L*HIDDEN + c];
                const unsigned short* hrow = hbU + c*HS;
                float vA = bv + w0*bfs(hrow[jA-dil])
                              + w1*bfs(hrow[jA    ])
                              + w2*bfs(hrow[jA+dil]);
                ytU[jA*YS + c] = f2bf(vA);
                if (actB) {
                    float vB = bv + w0*bfs(hrow[jB-dil])
                                  + w1*bfs(hrow[jB    ])
                                  + w2*bfs(hrow[jB+dil]);
                    ytU[jB*YS + c] = f2bf(vB);
                }
            }
        }
        __syncthreads();

        // ---- LN1 + GELU in place on Yt (dead cols zeroed) ----
        ln_pass(yt0, hb0, lnpp + (L*2+0)*HIDDEN, mk0, tid, jlo, jhi, true);
        ln_pass(yt1, hb1, lnpp + (L*2+0)*HIDDEN, mk1, tid, jlo, jhi, true);
        __syncthreads();

        // ---- pointwise 192x192 GEMM via MFMA, both tiles ----
        {
            f32x4 acc[2][3][2];
            #pragma unroll
            for (int u = 0; u < 2; ++u)
                #pragma unroll
                for (int mt = 0; mt < 3; ++mt)
                    #pragma unroll
                    for (int nt = 0; nt < 2; ++nt)
                        acc[u][mt][nt] = (f32x4){0.0f, 0.0f, 0.0f, 0.0f};

            #pragma unroll
            for (int u = 0; u < 2; ++u) {
                unsigned short* ytU = u ? yt1 : yt0;
                bf16x8 Bf[2][6];
                #pragma unroll
                for (int nt = 0; nt < 2; ++nt) {
                    const int n = ngrp*32 + nt*16 + l15;
                    const unsigned short* yr = ytU + n*YS;
                    #pragma unroll
                    for (int ks = 0; ks < 6; ++ks) {
                        const unsigned* p = (const unsigned*)(yr + ks*32 + hi*8);
                        union { unsigned uu[4]; bf16x8 v; } cv;
                        cv.uu[0] = p[0]; cv.uu[1] = p[1]; cv.uu[2] = p[2]; cv.uu[3] = p[3];
                        Bf[nt][ks] = cv.v;
                    }
                }
                if (preW) {
                    const unsigned short* wbl = wbf + (size_t)L*HIDDEN*HIDDEN;
                    #pragma unroll
                    for (int mt = 0; mt < 3; ++mt) {
                        const int m = mgrp*48 + mt*16 + l15;
                        const unsigned short* wr = wbl + (size_t)m*HIDDEN + hi*8;
                        #pragma unroll
                        for (int ks = 0; ks < 6; ++ks) {
                            bf16x8 a = *(const bf16x8*)(wr + ks*32);
                            acc[u][mt][0] = __builtin_amdgcn_mfma_f32_16x16x32_bf16(a, Bf[0][ks], acc[u][mt][0], 0, 0, 0);
                            acc[u][mt][1] = __builtin_amdgcn_mfma_f32_16x16x32_bf16(a, Bf[1][ks], acc[u][mt][1], 0, 0, 0);
                        }
                    }
                } else {
                    const float* wlayer = pww + (size_t)L*HIDDEN*HIDDEN;
                    #pragma unroll
                    for (int mt = 0; mt < 3; ++mt) {
                        const int m = mgrp*48 + mt*16 + l15;
                        const float* wr = wlayer + (size_t)m*HIDDEN + hi*8;
                        #pragma unroll
                        for (int ks = 0; ks < 6; ++ks) {
                            float4 a0 = *(const float4*)(wr + ks*32);
                            float4 a1 = *(const float4*)(wr + ks*32 + 4);
                            bf16x8 a;
                            a[0] = (short)f2bf(a0.x); a[1] = (short)f2bf(a0.y);
                            a[2] = (short)f2bf(a0.z); a[3] = (short)f2bf(a0.w);
                            a[4] = (short)f2bf(a1.x); a[5] = (short)f2bf(a1.y);
                            a[6] = (short)f2bf(a1.z); a[7] = (short)f2bf(a1.w);
                            acc[u][mt][0] = __builtin_amdgcn_mfma_f32_16x16x32_bf16(a, Bf[0][ks], acc[u][mt][0], 0, 0, 0);
                            acc[u][mt][1] = __builtin_amdgcn_mfma_f32_16x16x32_bf16(a, Bf[1][ks], acc[u][mt][1], 0, 0, 0);
                        }
                    }
                }
            }
            __syncthreads();   // all Yt reads complete before overwrite

            // bias + write z back over Yt (bf16)
            #pragma unroll
            for (int u = 0; u < 2; ++u) {
                unsigned short* ytU = u ? yt1 : yt0;
                #pragma unroll
                for (int mt = 0; mt < 3; ++mt) {
                    const int mrow = mgrp*48 + mt*16 + hi*4;
                    float4 bias = *(const float4*)(pwb + L*HIDDEN + mrow);
                    #pragma unroll
                    for (int nt = 0; nt < 2; ++nt) {
                        const int n = ngrp*32 + nt*16 + l15;
                        unsigned* zr = (unsigned*)(ytU + n*YS + mrow);
                        f32x4 v = acc[u][mt][nt];
                        zr[0] = packbf(v[0] + bias.x, v[1] + bias.y);
                        zr[1] = packbf(v[2] + bias.z, v[3] + bias.w);
                    }
                }
            }
        }
        __syncthreads();

        // ---- LN2 + GELU + residual (times mask) into hm (bf16) ----
        ln_pass(yt0, hb0, lnpp + (L*2+1)*HIDDEN, mk0, tid, jlo, jhi, false);
        ln_pass(yt1, hb1, lnpp + (L*2+1)*HIDDEN, mk1, tid, jlo, jhi, false);
        __syncthreads();
    }

    // ---- projection: p[o][j] = (proj_w @ hm + proj_b) * mask ----
    #pragma unroll
    for (int u = 0; u < 2; ++u) {
        unsigned short* hbU = u ? hb1 : hb0;
        float* pbU = (float*)(u ? yt1 : yt0);   // [TT][33], yt dead
        const float* mkU = u ? mk1 : mk0;
        const int j = lane;
        const int jj = HALO + j;
        const float mkv = mkU[jj];
        #pragma unroll
        for (int k = 0; k < 3; ++k) {
            const int o = wu + 12*k;
            if (o < PROJ) {
                const float* w = pjw + (size_t)o*HIDDEN;
                float acc = 0.0f;
                #pragma unroll 4
                for (int c = 0; c < HIDDEN; ++c)
                    acc = fmaf(w[c], bfs(hbU[c*HS + jj]), acc);
                pbU[j*33 + o] = (acc + pjb[o]) * mkv;
            }
        }
    }
    __syncthreads();

    // ---- spline epilogue: waves 0,1 -> tiles 0,1; scratch over hb ----
    float ladm = 0.0f;
    if (tid < 2*TT) {
        const int u = tid >> 6, j = tid & 63;
        float* pbU = (float*)(u ? yt1 : yt0);
        float* sc  = (float*)(u ? hb1 : hb0);
        const float* mkU = u ? mk1 : mk0;
        const int t = (tbb*2 + u)*TT + j;
        float* S  = sc + j*57;
        float* cw = S;          // 11
        float* ch = S + 11;     // 11
        float* wd = S + 22;     // 10
        float* ht = S + 32;     // 10
        float* dv = S + 42;     // 11

        const float x   = inputs[(size_t)b*2*NT + NT + t];
        const float fvv = inputs[(size_t)b*2*NT + t];
        const float mv  = mkU[HALO + j];

        {
            float uarr[NBINS]; float m = -1e30f;
            #pragma unroll
            for (int k = 0; k < NBINS; ++k) { uarr[k] = pbU[j*33 + k]*INV_SQRTF; m = fmaxf(m, uarr[k]); }
            float se = 0.0f;
            #pragma unroll
            for (int k = 0; k < NBINS; ++k) { uarr[k] = expf(uarr[k] - m); se += uarr[k]; }
            float inv = 1.0f/se, csum = 0.0f;
            cw[0] = -TAILF;
            #pragma unroll
            for (int k = 0; k < NBINS; ++k) {
                float wk = MIN_BIN + (1.0f - NBINS*MIN_BIN)*uarr[k]*inv;
                csum += wk;
                cw[k+1] = 2.0f*TAILF*csum - TAILF;
            }
            cw[NBINS] = TAILF;
            #pragma unroll
            for (int k = 0; k < NBINS; ++k) wd[k] = cw[k+1] - cw[k];
        }
        {
            float uarr[NBINS]; float m = -1e30f;
            #pragma unroll
            for (int k = 0; k < NBINS; ++k) { uarr[k] = pbU[j*33 + 10 + k]*INV_SQRTF; m = fmaxf(m, uarr[k]); }
            float se = 0.0f;
            #pragma unroll
            for (int k = 0; k < NBINS; ++k) { uarr[k] = expf(uarr[k] - m); se += uarr[k]; }
            float inv = 1.0f/se, csum = 0.0f;
            ch[0] = -TAILF;
            #pragma unroll
            for (int k = 0; k < NBINS; ++k) {
                float wk = MIN_BIN + (1.0f - NBINS*MIN_BIN)*uarr[k]*inv;
                csum += wk;
                ch[k+1] = 2.0f*TAILF*csum - TAILF;
            }
            ch[NBINS] = TAILF;
            #pragma unroll
            for (int k = 0; k < NBINS; ++k) ht[k] = ch[k+1] - ch[k];
        }
        {
            const float cpad = logf(expf(1.0f - MIN_DERF) - 1.0f);
            float edge = MIN_DERF + softplus_f(cpad);
            dv[0] = edge;
            #pragma unroll
            for (int k = 0; k < NBINS-1; ++k) dv[k+1] = MIN_DERF + softplus_f(pbU[j*33 + 2*NBINS + k]);
            dv[NBINS] = edge;
        }

        const float xi = fminf(fmaxf(x, -TAILF), TAILF);
        int cnt = 0;
        #pragma unroll
        for (int k = 0; k <= NBINS; ++k) {
            float bl = cw[k] + ((k == NBINS) ? 1e-6f : 0.0f);
            cnt += (xi >= bl) ? 1 : 0;
        }
        int bi = cnt - 1;
        bi = (bi < 0) ? 0 : ((bi > NBINS-1) ? NBINS-1 : bi);

        const float in_cw = cw[bi], in_w = wd[bi];
        const float in_ch = ch[bi], in_h = ht[bi];
        const float in_d  = ht[bi]/wd[bi];
        const float dA = dv[bi], dB = dv[bi+1];
        const float i1 = dA + dB - 2.0f*in_d;
        const float th = (xi - in_cw)/in_w;
        const float t1m = th*(1.0f - th);
        const float den = in_d + i1*t1m;
        const float outv = in_ch + in_h*(in_d*th*th + dA*t1m)/den;
        const float omt = 1.0f - th;
        const float dnum = in_d*in_d*(dB*th*th + 2.0f*in_d*t1m + dA*omt*omt);
        const float lad = logf(dnum) - 2.0f*logf(den);

        const bool inside = (x >= -TAILF) && (x <= TAILF);
        const float sec  = inside ? outv : x;
        ladm = (inside ? lad : 0.0f) * mv;

        out[(size_t)b*2*NT + t]      = fvv*mv;
        out[(size_t)b*2*NT + NT + t] = sec*mv;
    }
    if (tid < 128) {
        float tot = wave_sum(ladm);
        if (lane == 0) part[b*NTB + tbb*2 + (tid >> 6)] = tot;
    }
}

__global__ void ld_reduce(const float* __restrict__ part, float* __restrict__ ld) {
    int b = threadIdx.x;
    if (b < NB) {
        float s = 0.0f;
        for (int k = 0; k < NTB; ++k) s += part[b*NTB + k];
        ld[b] = s;
    }
}

extern "C" void kernel_launch(void* const* d_in, const int* in_sizes, int n_in,
                              void* d_out, int out_size, void* d_ws, size_t ws_size,
                              hipStream_t stream) {
    const float* inputs = (const float*)d_in[0];
    const float* pmask  = (const float*)d_in[1];
    const float* cpw    = (const float*)d_in[2];
    const float* cpb    = (const float*)d_in[3];
    const float* dww    = (const float*)d_in[4];
    const float* dwb    = (const float*)d_in[5];
    const float* pww    = (const float*)d_in[6];
    const float* pwb    = (const float*)d_in[7];
    const float* g1     = (const float*)d_in[8];
    const float* b1     = (const float*)d_in[9];
    const float* g2     = (const float*)d_in[10];
    const float* b2     = (const float*)d_in[11];
    const float* pjw    = (const float*)d_in[12];
    const float* pjb    = (const float*)d_in[13];
    float* out  = (float*)d_out;
    float* part = (float*)d_ws;

    const size_t need = WS_PART_BYTES + (size_t)WBF_ELEMS*2;
    const int preW = (ws_size >= need) ? 1 : 0;
    unsigned short* wbf = (unsigned short*)((char*)d_ws + WS_PART_BYTES);

    if (preW) {
        wconv_kernel<<<(WBF_ELEMS + 1023)/1024, 1024, 0, stream>>>(pww, wbf);
    }

    const size_t smem = (size_t)SMEM_FLOATS * sizeof(float);
    hipFuncSetAttribute(reinterpret_cast<const void*>(vits_fused),
                        hipFuncAttributeMaxDynamicSharedMemorySize, (int)smem);
    vits_fused<<<NB*NBLK, THREADS, smem, stream>>>(inputs, pmask, cpw, cpb, dww, dwb,
                                                   pww, pwb, g1, b1, g2, b2, pjw, pjb,
                                                   out, part, wbf, preW);
    ld_reduce<<<1, 64, 0, stream>>>(part, out + (size_t)NB*2*NT);
}

// Round 8
// 468.285 us; speedup vs baseline: 2.1095x; 1.1673x over previous
//
#include <hip/hip_runtime.h>
#include <hip/hip_bf16.h>
#include <math.h>

#define HIDDEN 192
#define NBINS 10
#define PROJ 29          // 3*NBINS-1
#define TAILF 5.0f
#define NLAYERS 3
#define NB 64
#define NT 2048
#define TT 64
#define HALO 13
#define COLS (TT + 2*HALO)   // 90
#define HS 94                 // hb bf16 row stride (47 dwords, odd -> conflict-free cols)
#define NPAD 96               // GEMM N padded
#define YS 194                // Yt bf16 row stride (97 dwords, odd)
#define NBLK (NT/(2*TT))      // 16 blocks per batch row (2 tiles per block)
#define NTB 32                // part entries per batch row
#define LN_EPS 1e-5f
#define MIN_BIN 1e-3f
#define MIN_DERF 1e-3f
#define INV_SQRTF 0.07216878364870323f   // 1/sqrt(192)
#define THREADS 1024
#define NWAVES 16

// LDS layout: shorts [hb0][hb1][yt0][yt1], then f32 [mk0][mk1][lnpp]
#define HB_SHORTS (HIDDEN*HS)                 // 18048
#define YT_SHORTS (NPAD*YS)                   // 18624
#define OFF_F32 ((2*HB_SHORTS + 2*YT_SHORTS)/2)   // dword index 36672
#define N_LNP (NLAYERS*2*HIDDEN)              // 1152 packed (g,b) dwords
#define SMEM_FLOATS (OFF_F32 + 2*COLS + N_LNP)    // 38004 dwords = 152016 B

#define WS_PART_BYTES 16384
#define WPW_ELEMS (NLAYERS*HIDDEN*HIDDEN)     // 110592
#define WPJ_ELEMS (32*HIDDEN)                 // 6144 (rows 29..31 zero)
#define WBF_TOTAL (WPW_ELEMS + WPJ_ELEMS)

typedef __attribute__((ext_vector_type(8))) short bf16x8;
typedef __attribute__((ext_vector_type(4))) float f32x4;

__device__ __forceinline__ unsigned short f2bf(float f) {
    __hip_bfloat16 h = __float2bfloat16(f);
    return __builtin_bit_cast(unsigned short, h);
}
__device__ __forceinline__ unsigned packbf(float lo, float hi_) {
    return (unsigned)f2bf(lo) | ((unsigned)f2bf(hi_) << 16);
}
__device__ __forceinline__ float bf2f_lo(unsigned u) {
    union { unsigned u; float f; } c; c.u = u << 16; return c.f;
}
__device__ __forceinline__ float bf2f_hi(unsigned u) {
    union { unsigned u; float f; } c; c.u = u & 0xffff0000u; return c.f;
}
__device__ __forceinline__ float bfs(unsigned short s) {
    union { unsigned u; float f; } c; c.u = ((unsigned)s) << 16; return c.f;
}

// exact GELU via A&S 7.1.26 rational erf (|err| < 1.5e-7), hw rcp/exp2
__device__ __forceinline__ float gelu_fast(float x) {
    const float az = fabsf(x) * 0.7071067811865476f;
    const float t  = __builtin_amdgcn_rcpf(fmaf(0.3275911f, az, 1.0f));
    float p = fmaf(1.061405429f, t, -1.453152027f);
    p = fmaf(p, t, 1.421413741f);
    p = fmaf(p, t, -0.284496736f);
    p = fmaf(p, t, 0.254829592f);
    p = p * t;
    const float e  = __builtin_amdgcn_exp2f(az*az*(-1.4426950408889634f));
    const float er = fmaf(-p, e, 1.0f);            // erf(|x|/sqrt2)
    const float se = (x >= 0.0f) ? er : -er;
    return 0.5f * x * (1.0f + se);
}
__device__ __forceinline__ float softplus_f(float x) {
    return (x > 20.0f) ? x : log1pf(expf(x));
}
__device__ __forceinline__ float wave_sum(float v) {
    #pragma unroll
    for (int o = 32; o > 0; o >>= 1) v += __shfl_xor(v, o, 64);
    return v;
}

// LN over channels for one column (8 lanes/col, 24 ch/lane) + GELU.
// toYt: write back to Yt (bf16); dead cols -> zeros (no math).
// else: residual-add gelu*mk into pre-masked hb (bf16); dead cols skipped.
__device__ __forceinline__ void ln_pass(unsigned short* ytU, unsigned short* hbU,
                                        const unsigned* gb, const float* mkU,
                                        int col, int q, int jlo, int jhi, bool toYt) {
    const int c0 = q * 24;
    unsigned short* row = ytU + col * YS;
    unsigned* wp = (unsigned*)(row + c0);
    if (col < jlo || col >= jhi) {
        if (toYt) {
            #pragma unroll
            for (int i = 0; i < 12; ++i) wp[i] = 0u;
        }
        return;
    }
    const unsigned* rp = (const unsigned*)(row + c0);
    float v[24];
    float s = 0.0f, ss = 0.0f;
    #pragma unroll
    for (int i = 0; i < 12; ++i) {
        unsigned u = rp[i];
        float a = bf2f_lo(u), c = bf2f_hi(u);
        v[2*i] = a; v[2*i+1] = c;
        s += a + c; ss += a*a + c*c;
    }
    s  += __shfl_xor(s, 1, 64);  s  += __shfl_xor(s, 2, 64);  s  += __shfl_xor(s, 4, 64);
    ss += __shfl_xor(ss, 1, 64); ss += __shfl_xor(ss, 2, 64); ss += __shfl_xor(ss, 4, 64);
    const float mu  = s * (1.0f/HIDDEN);
    const float var = fmaxf(ss * (1.0f/HIDDEN) - mu*mu, 0.0f);
    const float rs  = rsqrtf(var + LN_EPS);

    float gv[24], bv[24];
    #pragma unroll
    for (int i = 0; i < 24; ++i) {
        unsigned u = gb[c0 + i];
        gv[i] = bf2f_lo(u); bv[i] = bf2f_hi(u);
    }
    if (toYt) {
        #pragma unroll
        for (int i = 0; i < 12; ++i) {
            float r0 = gelu_fast((v[2*i]   - mu)*rs*gv[2*i]   + bv[2*i]);
            float r1 = gelu_fast((v[2*i+1] - mu)*rs*gv[2*i+1] + bv[2*i+1]);
            wp[i] = packbf(r0, r1);
        }
    } else {
        const float mkv = mkU[col];
        #pragma unroll
        for (int i = 0; i < 24; ++i) {
            float rr = gelu_fast((v[i] - mu)*rs*gv[i] + bv[i]) * mkv;
            const int idx = (c0 + i)*HS + col;
            hbU[idx] = f2bf(bfs(hbU[idx]) + rr);
        }
    }
}

__global__ void wconv_kernel(const float* __restrict__ pww, const float* __restrict__ pjw,
                             unsigned short* __restrict__ wbf) {
    int i = blockIdx.x * 1024 + threadIdx.x;
    if (i < WPW_ELEMS) {
        wbf[i] = f2bf(pww[i]);
    } else if (i < WBF_TOTAL) {
        int j = i - WPW_ELEMS;
        wbf[i] = (j < PROJ*HIDDEN) ? f2bf(pjw[j]) : (unsigned short)0;
    }
}

__global__ __launch_bounds__(THREADS) void vits_fused(
    const float* __restrict__ inputs, const float* __restrict__ pmask,
    const float* __restrict__ cpw, const float* __restrict__ cpb,
    const float* __restrict__ dww, const float* __restrict__ dwb,
    const float* __restrict__ pww, const float* __restrict__ pwb,
    const float* __restrict__ g1, const float* __restrict__ b1,
    const float* __restrict__ g2, const float* __restrict__ b2,
    const float* __restrict__ pjw, const float* __restrict__ pjb,
    float* __restrict__ out, float* __restrict__ part,
    const unsigned short* __restrict__ wbf, int preW)
{
    extern __shared__ float sm[];
    unsigned short* hb0 = (unsigned short*)sm;
    unsigned short* hb1 = hb0 + HB_SHORTS;
    unsigned short* yt0 = hb1 + HB_SHORTS;
    unsigned short* yt1 = yt0 + YT_SHORTS;
    float* mk0 = sm + OFF_F32;
    float* mk1 = mk0 + COLS;
    unsigned* lnpp = (unsigned*)(mk1 + COLS);   // [L][{ln1,ln2}][192] packed (g,b)

    const int tid = threadIdx.x;
    const int lane = tid & 63;
    const int wid = tid >> 6;
    const int wu  = __builtin_amdgcn_readfirstlane(wid);
    const int b   = blockIdx.x / NBLK;
    const int tbb = blockIdx.x % NBLK;

    // ---- stage packed LN params + mask tiles ----
    for (int i = tid; i < N_LNP; i += THREADS) {
        const int L = i / (2*HIDDEN);
        const int r = i - L*2*HIDDEN;
        const int which = r / HIDDEN;
        const int c = r - which*HIDDEN;
        const float* gp = which ? g2 : g1;
        const float* bp = which ? b2 : b1;
        lnpp[i] = packbf(gp[L*HIDDEN + c], bp[L*HIDDEN + c]);
    }
    for (int i = tid; i < 2*COLS; i += THREADS) {
        const int u = i / COLS, j = i - u*COLS;
        const int t = (tbb*2 + u)*TT - HALO + j;
        const bool in = (t >= 0) && (t < NT);
        (u ? mk1 : mk0)[j] = in ? pmask[(size_t)b*NT + t] : 0.0f;
    }
    __syncthreads();

    // ---- conv_pre: hm = (cpw*fv + cpb) * mask (pre-masked residual stream) ----
    #pragma unroll
    for (int u = 0; u < 2; ++u) {
        unsigned short* hbU = u ? hb1 : hb0;
        const float* mkU = u ? mk1 : mk0;
        const int t0u = (tbb*2 + u)*TT - HALO;
        float fA = 0.0f, fB = 0.0f;
        { int t = t0u + lane; if (t >= 0 && t < NT) fA = inputs[(size_t)b*2*NT + t]; }
        { int t = t0u + 64 + lane; if (lane + 64 < COLS && t >= 0 && t < NT) fB = inputs[(size_t)b*2*NT + t]; }
        const float mA = mkU[lane];
        const float mB = (lane + 64 < COLS) ? mkU[lane + 64] : 0.0f;
        for (int c = wu; c < HIDDEN; c += NWAVES) {
            const float wv = cpw[c], bv = cpb[c];
            hbU[c*HS + lane] = f2bf((wv*fA + bv)*mA);
            if (lane + 64 < COLS) hbU[c*HS + lane + 64] = f2bf((wv*fB + bv)*mB);
        }
    }
    __syncthreads();

    const int dils[NLAYERS]  = {1, 3, 9};
    const int mouts[NLAYERS] = {1, 4, 13};

    const int l15 = lane & 15, hi = lane >> 4;
    // GEMM wave partition: u = wu>>3, r = wu&7: mgrp = r&3 (48 rows), ngrp = r>>2 (48 cols)
    const int g_u = wu >> 3;
    const int mgrp = wu & 3;
    const int ngrp = (wu >> 2) & 1;

    // LN slot mapping (call A covers tile0 cols 0..95 + tile1 cols 0..31; call B tile1 cols 32..95)
    const int slot = tid >> 3, q8 = tid & 7;
    const int lnA_u = (slot >= 96);
    const int lnA_col = lnA_u ? (slot - 96) : slot;

    for (int L = 0; L < NLAYERS; ++L) {
        const int dil = dils[L];
        const int jlo = mouts[L], jhi = COLS - mouts[L];

        // ---- depthwise dilated conv + bias -> Yt (input pre-masked: no mk muls) ----
        #pragma unroll
        for (int u = 0; u < 2; ++u) {
            unsigned short* hbU = u ? hb1 : hb0;
            unsigned short* ytU = u ? yt1 : yt0;
            const int jA = jlo + lane;
            const int jB = jlo + 64 + lane;
            const bool actB = jB < jhi;
            for (int c = wu; c < HIDDEN; c += NWAVES) {
                const float* w = dww + ((size_t)L*HIDDEN + c)*3;
                const float w0 = w[0], w1 = w[1], w2 = w[2];
                const float bv = dwb[L*HIDDEN + c];
                const unsigned short* hrow = hbU + c*HS;
                float vA = bv + w0*bfs(hrow[jA-dil])
                              + w1*bfs(hrow[jA    ])
                              + w2*bfs(hrow[jA+dil]);
                ytU[jA*YS + c] = f2bf(vA);
                if (actB) {
                    float vB = bv + w0*bfs(hrow[jB-dil])
                                  + w1*bfs(hrow[jB    ])
                                  + w2*bfs(hrow[jB+dil]);
                    ytU[jB*YS + c] = f2bf(vB);
                }
            }
        }
        __syncthreads();

        // ---- LN1 + GELU in place on Yt (dead cols zeroed) ----
        {
            const unsigned* gb = lnpp + (L*2+0)*HIDDEN;
            ln_pass(lnA_u ? yt1 : yt0, lnA_u ? hb1 : hb0, gb, lnA_u ? mk1 : mk0,
                    lnA_col, q8, jlo, jhi, true);
            if (slot < 64)
                ln_pass(yt1, hb1, gb, mk1, slot + 32, q8, jlo, jhi, true);
        }
        __syncthreads();

        // ---- pointwise 192x192 GEMM via MFMA: wave = (tile, 48x48 block) ----
        {
            unsigned short* ytU = g_u ? yt1 : yt0;
            f32x4 acc[3][3];
            #pragma unroll
            for (int mt = 0; mt < 3; ++mt)
                #pragma unroll
                for (int nt = 0; nt < 3; ++nt)
                    acc[mt][nt] = (f32x4){0.0f, 0.0f, 0.0f, 0.0f};

            if (preW) {
                const unsigned short* wbl = wbf + (size_t)L*HIDDEN*HIDDEN;
                #pragma unroll
                for (int nt = 0; nt < 3; ++nt) {
                    const int n = ngrp*48 + nt*16 + l15;
                    const unsigned short* yr = ytU + n*YS;
                    bf16x8 Bk[6];
                    #pragma unroll
                    for (int ks = 0; ks < 6; ++ks) {
                        const unsigned* p = (const unsigned*)(yr + ks*32 + hi*8);
                        union { unsigned uu[4]; bf16x8 v; } cv;
                        cv.uu[0] = p[0]; cv.uu[1] = p[1]; cv.uu[2] = p[2]; cv.uu[3] = p[3];
                        Bk[ks] = cv.v;
                    }
                    #pragma unroll
                    for (int mt = 0; mt < 3; ++mt) {
                        const unsigned short* wr = wbl + (size_t)(mgrp*48 + mt*16 + l15)*HIDDEN + hi*8;
                        #pragma unroll
                        for (int ks = 0; ks < 6; ++ks) {
                            bf16x8 a = *(const bf16x8*)(wr + ks*32);
                            acc[mt][nt] = __builtin_amdgcn_mfma_f32_16x16x32_bf16(a, Bk[ks], acc[mt][nt], 0, 0, 0);
                        }
                    }
                }
            } else {
                const float* wlayer = pww + (size_t)L*HIDDEN*HIDDEN;
                #pragma unroll
                for (int nt = 0; nt < 3; ++nt) {
                    const int n = ngrp*48 + nt*16 + l15;
                    const unsigned short* yr = ytU + n*YS;
                    bf16x8 Bk[6];
                    #pragma unroll
                    for (int ks = 0; ks < 6; ++ks) {
                        const unsigned* p = (const unsigned*)(yr + ks*32 + hi*8);
                        union { unsigned uu[4]; bf16x8 v; } cv;
                        cv.uu[0] = p[0]; cv.uu[1] = p[1]; cv.uu[2] = p[2]; cv.uu[3] = p[3];
                        Bk[ks] = cv.v;
                    }
                    #pragma unroll
                    for (int mt = 0; mt < 3; ++mt) {
                        const float* wr = wlayer + (size_t)(mgrp*48 + mt*16 + l15)*HIDDEN + hi*8;
                        #pragma unroll
                        for (int ks = 0; ks < 6; ++ks) {
                            float4 a0 = *(const float4*)(wr + ks*32);
                            float4 a1 = *(const float4*)(wr + ks*32 + 4);
                            bf16x8 a;
                            a[0] = (short)f2bf(a0.x); a[1] = (short)f2bf(a0.y);
                            a[2] = (short)f2bf(a0.z); a[3] = (short)f2bf(a0.w);
                            a[4] = (short)f2bf(a1.x); a[5] = (short)f2bf(a1.y);
                            a[6] = (short)f2bf(a1.z); a[7] = (short)f2bf(a1.w);
                            acc[mt][nt] = __builtin_amdgcn_mfma_f32_16x16x32_bf16(a, Bk[ks], acc[mt][nt], 0, 0, 0);
                        }
                    }
                }
            }
            __syncthreads();   // all Yt reads complete before overwrite

            // bias + write z back over Yt (bf16)
            #pragma unroll
            for (int mt = 0; mt < 3; ++mt) {
                const int mrow = mgrp*48 + mt*16 + hi*4;
                float4 bias = *(const float4*)(pwb + L*HIDDEN + mrow);
                unsigned short* ytW = g_u ? yt1 : yt0;
                #pragma unroll
                for (int nt = 0; nt < 3; ++nt) {
                    const int n = ngrp*48 + nt*16 + l15;
                    unsigned* zr = (unsigned*)(ytW + n*YS + mrow);
                    f32x4 v = acc[mt][nt];
                    zr[0] = packbf(v[0] + bias.x, v[1] + bias.y);
                    zr[1] = packbf(v[2] + bias.z, v[3] + bias.w);
                }
            }
        }
        __syncthreads();

        // ---- LN2 + GELU + residual (times mask) into hm (bf16) ----
        {
            const unsigned* gb = lnpp + (L*2+1)*HIDDEN;
            ln_pass(lnA_u ? yt1 : yt0, lnA_u ? hb1 : hb0, gb, lnA_u ? mk1 : mk0,
                    lnA_col, q8, jlo, jhi, false);
            if (slot < 64)
                ln_pass(yt1, hb1, gb, mk1, slot + 32, q8, jlo, jhi, false);
        }
        __syncthreads();
    }

    // ---- projection: p[o][j] = (proj_w @ hm + proj_b) * mask ----
    if (preW) {
        // wave task: u = wu>>3, mt = (wu>>2)&1, nt4 = wu&3; 6 MFMAs per wave
        const unsigned short* wpj = wbf + WPW_ELEMS;
        const int p_u = wu >> 3;
        const int p_mt = (wu >> 2) & 1;
        const int p_nt = wu & 3;
        unsigned short* hbU = p_u ? hb1 : hb0;
        float* pbU = (float*)(p_u ? yt1 : yt0);
        const float* mkU = p_u ? mk1 : mk0;
        const int j = p_nt*16 + l15;
        const int jj = HALO + j;
        f32x4 pacc = (f32x4){0.0f, 0.0f, 0.0f, 0.0f};
        #pragma unroll
        for (int ks = 0; ks < 6; ++ks) {
            bf16x8 a = *(const bf16x8*)(wpj + (size_t)(p_mt*16 + l15)*HIDDEN + ks*32 + hi*8);
            bf16x8 bb;
            #pragma unroll
            for (int e = 0; e < 8; ++e)
                bb[e] = (short)hbU[(ks*32 + hi*8 + e)*HS + jj];
            pacc = __builtin_amdgcn_mfma_f32_16x16x32_bf16(a, bb, pacc, 0, 0, 0);
        }
        const float mkv = mkU[jj];
        #pragma unroll
        for (int r = 0; r < 4; ++r) {
            const int o = p_mt*16 + hi*4 + r;
            if (o < PROJ)
                pbU[j*33 + o] = (pacc[r] + pjb[o]) * mkv;
        }
    } else {
        #pragma unroll
        for (int u = 0; u < 2; ++u) {
            unsigned short* hbU = u ? hb1 : hb0;
            float* pbU = (float*)(u ? yt1 : yt0);
            const float* mkU = u ? mk1 : mk0;
            const int j = lane;
            const int jj = HALO + j;
            const float mkv = mkU[jj];
            #pragma unroll
            for (int k = 0; k < 2; ++k) {
                const int o = wu + 16*k;
                if (o < PROJ) {
                    const float* w = pjw + (size_t)o*HIDDEN;
                    float acc = 0.0f;
                    #pragma unroll 4
                    for (int c = 0; c < HIDDEN; ++c)
                        acc = fmaf(w[c], bfs(hbU[c*HS + jj]), acc);
                    pbU[j*33 + o] = (acc + pjb[o]) * mkv;
                }
            }
        }
    }
    __syncthreads();

    // ---- spline epilogue: waves 0,1 -> tiles 0,1; scratch over hb ----
    float ladm = 0.0f;
    if (tid < 2*TT) {
        const int u = tid >> 6, j = tid & 63;
        float* pbU = (float*)(u ? yt1 : yt0);
        float* sc  = (float*)(u ? hb1 : hb0);
        const float* mkU = u ? mk1 : mk0;
        const int t = (tbb*2 + u)*TT + j;
        float* S  = sc + j*57;
        float* cw = S;          // 11
        float* ch = S + 11;     // 11
        float* wd = S + 22;     // 10
        float* ht = S + 32;     // 10
        float* dv = S + 42;     // 11

        const float x   = inputs[(size_t)b*2*NT + NT + t];
        const float fvv = inputs[(size_t)b*2*NT + t];
        const float mv  = mkU[HALO + j];

        {
            float uarr[NBINS]; float m = -1e30f;
            #pragma unroll
            for (int k = 0; k < NBINS; ++k) { uarr[k] = pbU[j*33 + k]*INV_SQRTF; m = fmaxf(m, uarr[k]); }
            float se = 0.0f;
            #pragma unroll
            for (int k = 0; k < NBINS; ++k) { uarr[k] = expf(uarr[k] - m); se += uarr[k]; }
            float inv = 1.0f/se, csum = 0.0f;
            cw[0] = -TAILF;
            #pragma unroll
            for (int k = 0; k < NBINS; ++k) {
                float wk = MIN_BIN + (1.0f - NBINS*MIN_BIN)*uarr[k]*inv;
                csum += wk;
                cw[k+1] = 2.0f*TAILF*csum - TAILF;
            }
            cw[NBINS] = TAILF;
            #pragma unroll
            for (int k = 0; k < NBINS; ++k) wd[k] = cw[k+1] - cw[k];
        }
        {
            float uarr[NBINS]; float m = -1e30f;
            #pragma unroll
            for (int k = 0; k < NBINS; ++k) { uarr[k] = pbU[j*33 + 10 + k]*INV_SQRTF; m = fmaxf(m, uarr[k]); }
            float se = 0.0f;
            #pragma unroll
            for (int k = 0; k < NBINS; ++k) { uarr[k] = expf(uarr[k] - m); se += uarr[k]; }
            float inv = 1.0f/se, csum = 0.0f;
            ch[0] = -TAILF;
            #pragma unroll
            for (int k = 0; k < NBINS; ++k) {
                float wk = MIN_BIN + (1.0f - NBINS*MIN_BIN)*uarr[k]*inv;
                csum += wk;
                ch[k+1] = 2.0f*TAILF*csum - TAILF;
            }
            ch[NBINS] = TAILF;
            #pragma unroll
            for (int k = 0; k < NBINS; ++k) ht[k] = ch[k+1] - ch[k];
        }
        {
            const float cpad = logf(expf(1.0f - MIN_DERF) - 1.0f);
            float edge = MIN_DERF + softplus_f(cpad);
            dv[0] = edge;
            #pragma unroll
            for (int k = 0; k < NBINS-1; ++k) dv[k+1] = MIN_DERF + softplus_f(pbU[j*33 + 2*NBINS + k]);
            dv[NBINS] = edge;
        }

        const float xi = fminf(fmaxf(x, -TAILF), TAILF);
        int cnt = 0;
        #pragma unroll
        for (int k = 0; k <= NBINS; ++k) {
            float bl = cw[k] + ((k == NBINS) ? 1e-6f : 0.0f);
            cnt += (xi >= bl) ? 1 : 0;
        }
        int bi = cnt - 1;
        bi = (bi < 0) ? 0 : ((bi > NBINS-1) ? NBINS-1 : bi);

        const float in_cw = cw[bi], in_w = wd[bi];
        const float in_ch = ch[bi], in_h = ht[bi];
        const float in_d  = ht[bi]/wd[bi];
        const float dA = dv[bi], dB = dv[bi+1];
        const float i1 = dA + dB - 2.0f*in_d;
        const float th = (xi - in_cw)/in_w;
        const float t1m = th*(1.0f - th);
        const float den = in_d + i1*t1m;
        const float outv = in_ch + in_h*(in_d*th*th + dA*t1m)/den;
        const float omt = 1.0f - th;
        const float dnum = in_d*in_d*(dB*th*th + 2.0f*in_d*t1m + dA*omt*omt);
        const float lad = logf(dnum) - 2.0f*logf(den);

        const bool inside = (x >= -TAILF) && (x <= TAILF);
        const float sec  = inside ? outv : x;
        ladm = (inside ? lad : 0.0f) * mv;

        out[(size_t)b*2*NT + t]      = fvv*mv;
        out[(size_t)b*2*NT + NT + t] = sec*mv;
    }
    if (tid < 128) {
        float tot = wave_sum(ladm);
        if (lane == 0) part[b*NTB + tbb*2 + (tid >> 6)] = tot;
    }
}

__global__ void ld_reduce(const float* __restrict__ part, float* __restrict__ ld) {
    int b = threadIdx.x;
    if (b < NB) {
        float s = 0.0f;
        for (int k = 0; k < NTB; ++k) s += part[b*NTB + k];
        ld[b] = s;
    }
}

extern "C" void kernel_launch(void* const* d_in, const int* in_sizes, int n_in,
                              void* d_out, int out_size, void* d_ws, size_t ws_size,
                              hipStream_t stream) {
    const float* inputs = (const float*)d_in[0];
    const float* pmask  = (const float*)d_in[1];
    const float* cpw    = (const float*)d_in[2];
    const float* cpb    = (const float*)d_in[3];
    const float* dww    = (const float*)d_in[4];
    const float* dwb    = (const float*)d_in[5];
    const float* pww    = (const float*)d_in[6];
    const float* pwb    = (const float*)d_in[7];
    const float* g1     = (const float*)d_in[8];
    const float* b1     = (const float*)d_in[9];
    const float* g2     = (const float*)d_in[10];
    const float* b2     = (const float*)d_in[11];
    const float* pjw    = (const float*)d_in[12];
    const float* pjb    = (const float*)d_in[13];
    float* out  = (float*)d_out;
    float* part = (float*)d_ws;

    const size_t need = WS_PART_BYTES + (size_t)WBF_TOTAL*2;
    const int preW = (ws_size >= need) ? 1 : 0;
    unsigned short* wbf = (unsigned short*)((char*)d_ws + WS_PART_BYTES);

    if (preW) {
        wconv_kernel<<<(WBF_TOTAL + 1023)/1024, 1024, 0, stream>>>(pww, pjw, wbf);
    }

    const size_t smem = (size_t)SMEM_FLOATS * sizeof(float);
    hipFuncSetAttribute(reinterpret_cast<const void*>(vits_fused),
                        hipFuncAttributeMaxDynamicSharedMemorySize, (int)smem);
    vits_fused<<<NB*NBLK, THREADS, smem, stream>>>(inputs, pmask, cpw, cpb, dww, dwb,
                                                   pww, pwb, g1, b1, g2, b2, pjw, pjb,
                                                   out, part, wbf, preW);
    ld_reduce<<<1, 64, 0, stream>>>(part, out + (size_t)NB*2*NT);
}